// Round 9
// baseline (155.977 us; speedup 1.0000x reference)
//
#include <hip/hip_runtime.h>
#include <math.h>

// N=1024, X_DIM=HID=Y_DIM=256. 2 launches, 256 blocks each.
// K1 (R8 proven): layer-1 full-K GEMM (64x32, 2 heads), bias+relu, Dekker
//   split stores (h hi/lo), w2 pre-split, 4-row moment partials, zero-inits.
// K2: layer-2 conversion-free GEMM + FUSED epilogue via pair tickets:
//   2nd finisher of each (rt,ct) mu/lv pair computes the CLUB terms for its
//   64x32 patch -> rowAcc atomics; last of 8 per rowTile -> relu+sum -> out.
constexpr int LSB = 72;  // bf16 LDS row stride (144 B) — benign banks

typedef short bf16x8 __attribute__((ext_vector_type(8)));
typedef float f32x4  __attribute__((ext_vector_type(4)));

__device__ __forceinline__ unsigned short f2bf_rne(float f) {
    unsigned u = __float_as_uint(f);
    unsigned r = (u + 0x7fff + ((u >> 16) & 1)) >> 16;
    return (unsigned short)r;
}
__device__ __forceinline__ float bf2f(unsigned short h) {
    return __uint_as_float(((unsigned)h) << 16);
}
__device__ __forceinline__ void split4(float4 v, ushort4& hi, ushort4& lo) {
    hi.x = f2bf_rne(v.x); lo.x = f2bf_rne(v.x - bf2f(hi.x));
    hi.y = f2bf_rne(v.y); lo.y = f2bf_rne(v.y - bf2f(hi.y));
    hi.z = f2bf_rne(v.z); lo.z = f2bf_rne(v.z - bf2f(hi.z));
    hi.w = f2bf_rne(v.w); lo.w = f2bf_rne(v.w - bf2f(hi.w));
}

// Block decode (both kernels): head=bid&1, colTile=(bid>>1)&7 (32 wide),
// rowTile=bid>>4 (64 tall). 16*8*2 = 256 blocks, full K=256.

// ---------------------------------------------------------------------------
// K1: layer-1 GEMM, 64x32 tile, K=256, MFMA bf16 split-fp32 (hh+hl+lh).
// ---------------------------------------------------------------------------
__global__ __launch_bounds__(256)
void k1_layer1(const float* __restrict__ x,
               const float* __restrict__ w1m, const float* __restrict__ w1l,
               const float* __restrict__ b1m, const float* __restrict__ b1l,
               const float* __restrict__ w2m, const float* __restrict__ w2l,
               unsigned short* __restrict__ hmH, unsigned short* __restrict__ hmL,
               unsigned short* __restrict__ hlH, unsigned short* __restrict__ hlL,
               unsigned short* __restrict__ w2mH, unsigned short* __restrict__ w2mL,
               unsigned short* __restrict__ w2lH, unsigned short* __restrict__ w2lL,
               const float* __restrict__ y, const float* __restrict__ z,
               float* __restrict__ pA1, float* __restrict__ pB1,
               float* __restrict__ rowAcc, int* __restrict__ pairTick,
               int* __restrict__ rowTick, float* __restrict__ out) {
    const int bid = blockIdx.x, t = threadIdx.x;
    const int head = bid & 1, ct = (bid >> 1) & 7, rt = bid >> 4;
    const int rowBase = rt * 64, colBase = ct * 32;
    const int w = t >> 6, lane = t & 63, quad = lane >> 4, mr = lane & 15;

    const float* Bw   = head ? w1l : w1m;
    const float* bias = head ? b1l : b1m;
    unsigned short* CH = head ? hlH : hmH;
    unsigned short* CL = head ? hlL : hmL;

    __shared__ __align__(16) unsigned short Ah[64][LSB], Al[64][LSB];
    __shared__ __align__(16) unsigned short Bh[32][LSB], Bl[32][LSB];

    f32x4 acc[2] = {{0.f, 0.f, 0.f, 0.f}, {0.f, 0.f, 0.f, 0.f}};

    for (int kt = 0; kt < 256; kt += 64) {
#pragma unroll
        for (int p = 0; p < 4; p++) {
            int idx = p * 256 + t;
            int r = idx >> 4, k4 = idx & 15;
            float4 av = *(const float4*)&x[(rowBase + r) * 256 + kt + k4 * 4];
            ushort4 h4, l4;
            split4(av, h4, l4);
            *(ushort4*)&Ah[r][k4 * 4] = h4;
            *(ushort4*)&Al[r][k4 * 4] = l4;
            if (p < 2) {   // r in [0,32)
                float4 bv = *(const float4*)&Bw[(colBase + r) * 256 + kt + k4 * 4];
                split4(bv, h4, l4);
                *(ushort4*)&Bh[r][k4 * 4] = h4;
                *(ushort4*)&Bl[r][k4 * 4] = l4;
            }
        }
        __syncthreads();

#pragma unroll
        for (int kk = 0; kk < 64; kk += 32) {
            int ko = kk + quad * 8;
            bf16x8 ah = *(const bf16x8*)&Ah[w * 16 + mr][ko];
            bf16x8 al = *(const bf16x8*)&Al[w * 16 + mr][ko];
#pragma unroll
            for (int nt = 0; nt < 2; nt++) {
                bf16x8 bh = *(const bf16x8*)&Bh[nt * 16 + mr][ko];
                bf16x8 bl = *(const bf16x8*)&Bl[nt * 16 + mr][ko];
                acc[nt] = __builtin_amdgcn_mfma_f32_16x16x32_bf16(ah, bh, acc[nt], 0, 0, 0);
                acc[nt] = __builtin_amdgcn_mfma_f32_16x16x32_bf16(ah, bl, acc[nt], 0, 0, 0);
                acc[nt] = __builtin_amdgcn_mfma_f32_16x16x32_bf16(al, bh, acc[nt], 0, 0, 0);
            }
        }
        __syncthreads();
    }

    // bias + relu -> Dekker split -> hi/lo stores (C/D: col=lane&15, row=quad*4+reg)
#pragma unroll
    for (int nt = 0; nt < 2; nt++) {
        int cg = colBase + nt * 16 + mr;
        float bb = bias[cg];
#pragma unroll
        for (int reg = 0; reg < 4; reg++) {
            int rg = rowBase + w * 16 + quad * 4 + reg;
            float v = fmaxf(acc[nt][reg] + bb, 0.f);
            unsigned short hi = f2bf_rne(v);
            CH[rg * 256 + cg] = hi;
            CL[rg * 256 + cg] = f2bf_rne(v - bf2f(hi));
        }
    }

    // w2 pre-split: 1 elem/thread from each of w2m, w2l
    {
        int off = bid * 256 + t;
        float vm = w2m[off], vl = w2l[off];
        unsigned short h1 = f2bf_rne(vm);
        w2mH[off] = h1; w2mL[off] = f2bf_rne(vm - bf2f(h1));
        unsigned short h2 = f2bf_rne(vl);
        w2lH[off] = h2; w2lL[off] = f2bf_rne(vl - bf2f(h2));
    }

    // moment partials over rows [4*bid, 4*bid+4)
    {
        float sA = 0.f, sB = 0.f;
        int base = bid * 4 * 256 + t;
#pragma unroll
        for (int j = 0; j < 4; j++) {
            float yv = y[base + j * 256];
            float zv = z[base + j * 256];
            sA += yv * yv + zv * zv;
            sB += yv + zv;
        }
        pA1[bid * 256 + t] = sA;
        pB1[bid * 256 + t] = sB;
    }

    // zero-inits consumed by K2
    if (bid < 4) rowAcc[bid * 256 + t] = 0.f;
    if (bid == 4) {
        if (t < 128) pairTick[t] = 0;
        else if (t < 144) rowTick[t - 128] = 0;
    }
    if (bid == 0 && t == 0) out[0] = 0.f;
}

// ---------------------------------------------------------------------------
// K2: layer-2 GEMM (conversion-free) + fused CLUB epilogue via pair tickets.
// ---------------------------------------------------------------------------
__global__ __launch_bounds__(256)
void k2_fused(const unsigned short* __restrict__ hmH, const unsigned short* __restrict__ hmL,
              const unsigned short* __restrict__ hlH, const unsigned short* __restrict__ hlL,
              const unsigned short* __restrict__ w2mH, const unsigned short* __restrict__ w2mL,
              const unsigned short* __restrict__ w2lH, const unsigned short* __restrict__ w2lL,
              const float* __restrict__ b2m, const float* __restrict__ b2l,
              float* __restrict__ muO, float* __restrict__ lvO,
              const float* __restrict__ y, const float* __restrict__ z,
              const float* __restrict__ pA1, const float* __restrict__ pB1,
              float* __restrict__ rowAcc, int* __restrict__ pairTick,
              int* __restrict__ rowTick, float* __restrict__ out) {
    const int bid = blockIdx.x, t = threadIdx.x;
    const int head = bid & 1, ct = (bid >> 1) & 7, rt = bid >> 4;
    const int rowBase = rt * 64, colBase = ct * 32;
    const int w = t >> 6, lane = t & 63, quad = lane >> 4, mr = lane & 15;

    const unsigned short* AH = head ? hlH : hmH;
    const unsigned short* AL = head ? hlL : hmL;
    const unsigned short* BH = head ? w2lH : w2mH;
    const unsigned short* BL = head ? w2lL : w2mL;
    const float* bias = head ? b2l : b2m;
    float* C = head ? lvO : muO;

    __shared__ __align__(16) unsigned short Ah[64][LSB], Al[64][LSB];
    __shared__ __align__(16) unsigned short Bh[32][LSB], Bl[32][LSB];
    __shared__ float part[16][32];
    __shared__ float mAf[32], mBf[32];
    __shared__ int oldTick, oldRt;

    f32x4 acc[2] = {{0.f, 0.f, 0.f, 0.f}, {0.f, 0.f, 0.f, 0.f}};

    for (int kt = 0; kt < 256; kt += 64) {
#pragma unroll
        for (int p = 0; p < 4; p++) {
            int idx = p * 256 + t;
            int r = idx >> 4, k4 = idx & 15;
            int off = (rowBase + r) * 256 + kt + k4 * 4;
            *(ushort4*)&Ah[r][k4 * 4] = *(const ushort4*)&AH[off];
            *(ushort4*)&Al[r][k4 * 4] = *(const ushort4*)&AL[off];
            if (p < 2) {
                int boff = (colBase + r) * 256 + kt + k4 * 4;
                *(ushort4*)&Bh[r][k4 * 4] = *(const ushort4*)&BH[boff];
                *(ushort4*)&Bl[r][k4 * 4] = *(const ushort4*)&BL[boff];
            }
        }
        __syncthreads();

#pragma unroll
        for (int kk = 0; kk < 64; kk += 32) {
            int ko = kk + quad * 8;
            bf16x8 ah = *(const bf16x8*)&Ah[w * 16 + mr][ko];
            bf16x8 al = *(const bf16x8*)&Al[w * 16 + mr][ko];
#pragma unroll
            for (int nt = 0; nt < 2; nt++) {
                bf16x8 bh = *(const bf16x8*)&Bh[nt * 16 + mr][ko];
                bf16x8 bl = *(const bf16x8*)&Bl[nt * 16 + mr][ko];
                acc[nt] = __builtin_amdgcn_mfma_f32_16x16x32_bf16(ah, bh, acc[nt], 0, 0, 0);
                acc[nt] = __builtin_amdgcn_mfma_f32_16x16x32_bf16(ah, bl, acc[nt], 0, 0, 0);
                acc[nt] = __builtin_amdgcn_mfma_f32_16x16x32_bf16(al, bh, acc[nt], 0, 0, 0);
            }
        }
        __syncthreads();
    }

    // store own mu/lv tile
#pragma unroll
    for (int nt = 0; nt < 2; nt++) {
        int cg = colBase + nt * 16 + mr;
        float bb = bias[cg];
#pragma unroll
        for (int reg = 0; reg < 4; reg++) {
            int rg = rowBase + w * 16 + quad * 4 + reg;
            C[rg * 256 + cg] = acc[nt][reg] + bb;
        }
    }

    // ---- pair ticket: 2nd finisher of (rt,ct) runs the patch epilogue ----
    __threadfence();
    __syncthreads();
    if (t == 0) oldTick = atomicAdd(&pairTick[bid >> 1], 1);
    __syncthreads();
    if (oldTick == 0) return;          // first finisher exits
    __threadfence();                   // acquire partner's tile writes

    // moment fold for cols [ct*32, +32): 256 partial sets -> means
    {
        int c = t & 31, g = t >> 5;    // g 0..7
        int gc = ct * 32 + c;
        float sA = 0.f, sB = 0.f;
        for (int j = 0; j < 32; j++) {
            int s = g * 32 + j;
            sA += pA1[s * 256 + gc];
            sB += pB1[s * 256 + gc];
        }
        part[g][c] = sA;
        part[8 + g][c] = sB;
    }
    __syncthreads();
    if (t < 32) {
        float sA = 0.f, sB = 0.f;
#pragma unroll
        for (int g = 0; g < 8; g++) { sA += part[g][t]; sB += part[8 + g][t]; }
        mAf[t] = sA * (1.f / 1024.f);
        mBf[t] = sB * (1.f / 1024.f);
    }
    __syncthreads();

    // CLUB terms for the 64x32 patch; reduce over 32 cols -> rowAcc
    {
        int col = t & 31, gcol = colBase + col;
        float mA = mAf[col], mB = mBf[col];
#pragma unroll
        for (int r8 = 0; r8 < 8; r8++) {
            int grow = rowBase + (t >> 5) * 8 + r8;
            int o = grow * 256 + gcol;
            float m  = muO[o];
            float lv = tanhf(lvO[o]);
            float iv = 0.5f * expf(-lv);       // 1/(2*exp(logvar))
            float yv = y[o];
            float zv = z[o];
            float Mt = mA - 2.f * m * mB + 2.f * m * m;
            float dy = m - yv, dz = m - zv;
            float term = iv * (Mt - dy * dy - dz * dz);
#pragma unroll
            for (int msk = 16; msk; msk >>= 1)
                term += __shfl_xor(term, msk, 32);
            if (col == 0) atomicAdd(&rowAcc[grow], term);
        }
    }

    // ---- row ticket: last of 8 patch-epilogues per rowTile finalizes ----
    __threadfence();
    __syncthreads();
    if (t == 0) oldRt = atomicAdd(&rowTick[rt], 1);
    __syncthreads();
    if (oldRt != 7) return;
    __threadfence();

    if (t < 64) {
        float v = fmaxf(__hip_atomic_load(&rowAcc[rt * 64 + t],
                                          __ATOMIC_RELAXED,
                                          __HIP_MEMORY_SCOPE_AGENT), 0.f);
#pragma unroll
        for (int msk = 32; msk; msk >>= 1)
            v += __shfl_xor(v, msk, 64);
        if (t == 0) atomicAdd(out, v * (1.f / 1024.f));
    }
}

// ---------------------------------------------------------------------------
extern "C" void kernel_launch(void* const* d_in, const int* in_sizes, int n_in,
                              void* d_out, int out_size, void* d_ws, size_t ws_size,
                              hipStream_t stream) {
    const float* x   = (const float*)d_in[0];
    const float* y   = (const float*)d_in[1];
    const float* zs  = (const float*)d_in[2];
    const float* w1m = (const float*)d_in[3];
    const float* b1m = (const float*)d_in[4];
    const float* w2m = (const float*)d_in[5];
    const float* b2m = (const float*)d_in[6];
    const float* w1l = (const float*)d_in[7];
    const float* b1l = (const float*)d_in[8];
    const float* w2l = (const float*)d_in[9];
    const float* b2l = (const float*)d_in[10];
    float* out = (float*)d_out;

    char* ws = (char*)d_ws;
    float* pA1     = (float*)(ws);                     // 256 KB
    float* pB1     = (float*)(ws + (256u << 10));      // 256 KB
    float* rowAcc  = (float*)(ws + (512u << 10));      // 4 KB
    int*   pairTick= (int*)(ws + (516u << 10));        // 512 B
    int*   rowTick = (int*)(ws + (517u << 10));        // 64 B
    unsigned short* hmH = (unsigned short*)(ws + (1024u << 10));  // 512 KB each
    unsigned short* hmL = (unsigned short*)(ws + (1536u << 10));
    unsigned short* hlH = (unsigned short*)(ws + (2048u << 10));
    unsigned short* hlL = (unsigned short*)(ws + (2560u << 10));
    unsigned short* w2mH = (unsigned short*)(ws + (3072u << 10)); // 128 KB each
    unsigned short* w2mL = (unsigned short*)(ws + (3200u << 10));
    unsigned short* w2lH = (unsigned short*)(ws + (3328u << 10));
    unsigned short* w2lL = (unsigned short*)(ws + (3456u << 10));
    float* muO = (float*)(ws + (4096u << 10));         // 1 MB
    float* lvO = (float*)(ws + (5120u << 10));         // 1 MB

    k1_layer1<<<256, 256, 0, stream>>>(x, w1m, w1l, b1m, b1l, w2m, w2l,
                                       hmH, hmL, hlH, hlL,
                                       w2mH, w2mL, w2lH, w2lL,
                                       y, zs, pA1, pB1,
                                       rowAcc, pairTick, rowTick, out);
    k2_fused<<<256, 256, 0, stream>>>(hmH, hmL, hlH, hlL,
                                      w2mH, w2mL, w2lH, w2lL,
                                      b2m, b2l, muO, lvO,
                                      y, zs, pA1, pB1,
                                      rowAcc, pairTick, rowTick, out);
}

// Round 10
// 98.462 us; speedup vs baseline: 1.5841x; 1.5841x over previous
//
#include <hip/hip_runtime.h>
#include <math.h>

// N=1024, X_DIM=HID=Y_DIM=256. 3 launches. Lesson from R4/R9: NO intra-kernel
// cross-block dataflow (device-scope fences = L2 writeback storms on gfx950);
// kernel boundaries are the only cheap device-wide sync.
//   K1 (R8 proven): layer-1 full-K GEMM (64x32, 2 heads), bias+relu, Dekker
//     split stores, w2 pre-split, 4-row moment partials, rowAcc zero.
//   K2: layer-2 GEMM with BOTH heads per block (32x32 patch) + in-block CLUB
//     epilogue -> fire-and-forget atomicAdd into rowAcc. No fences.
//   K3: 1 block: relu(rowAcc) sum -> out.
constexpr int LSB = 72;  // bf16 LDS row stride (144 B) — benign banks

typedef short bf16x8 __attribute__((ext_vector_type(8)));
typedef float f32x4  __attribute__((ext_vector_type(4)));

__device__ __forceinline__ unsigned short f2bf_rne(float f) {
    unsigned u = __float_as_uint(f);
    unsigned r = (u + 0x7fff + ((u >> 16) & 1)) >> 16;
    return (unsigned short)r;
}
__device__ __forceinline__ float bf2f(unsigned short h) {
    return __uint_as_float(((unsigned)h) << 16);
}
__device__ __forceinline__ void split4(float4 v, ushort4& hi, ushort4& lo) {
    hi.x = f2bf_rne(v.x); lo.x = f2bf_rne(v.x - bf2f(hi.x));
    hi.y = f2bf_rne(v.y); lo.y = f2bf_rne(v.y - bf2f(hi.y));
    hi.z = f2bf_rne(v.z); lo.z = f2bf_rne(v.z - bf2f(hi.z));
    hi.w = f2bf_rne(v.w); lo.w = f2bf_rne(v.w - bf2f(hi.w));
}

// ---------------------------------------------------------------------------
// K1: layer-1 GEMM, 64x32 tile, K=256, MFMA bf16 split-fp32 (hh+hl+lh).
// decode: head=bid&1, colTile=(bid>>1)&7 (32 wide), rowTile=bid>>4 (64 tall).
// ---------------------------------------------------------------------------
__global__ __launch_bounds__(256)
void k1_layer1(const float* __restrict__ x,
               const float* __restrict__ w1m, const float* __restrict__ w1l,
               const float* __restrict__ b1m, const float* __restrict__ b1l,
               const float* __restrict__ w2m, const float* __restrict__ w2l,
               unsigned short* __restrict__ hmH, unsigned short* __restrict__ hmL,
               unsigned short* __restrict__ hlH, unsigned short* __restrict__ hlL,
               unsigned short* __restrict__ w2mH, unsigned short* __restrict__ w2mL,
               unsigned short* __restrict__ w2lH, unsigned short* __restrict__ w2lL,
               const float* __restrict__ y, const float* __restrict__ z,
               float* __restrict__ pA1, float* __restrict__ pB1,
               float* __restrict__ rowAcc) {
    const int bid = blockIdx.x, t = threadIdx.x;
    const int head = bid & 1, ct = (bid >> 1) & 7, rt = bid >> 4;
    const int rowBase = rt * 64, colBase = ct * 32;
    const int w = t >> 6, lane = t & 63, quad = lane >> 4, mr = lane & 15;

    const float* Bw   = head ? w1l : w1m;
    const float* bias = head ? b1l : b1m;
    unsigned short* CH = head ? hlH : hmH;
    unsigned short* CL = head ? hlL : hmL;

    __shared__ __align__(16) unsigned short Ah[64][LSB], Al[64][LSB];
    __shared__ __align__(16) unsigned short Bh[32][LSB], Bl[32][LSB];

    f32x4 acc[2] = {{0.f, 0.f, 0.f, 0.f}, {0.f, 0.f, 0.f, 0.f}};

    for (int kt = 0; kt < 256; kt += 64) {
#pragma unroll
        for (int p = 0; p < 4; p++) {
            int idx = p * 256 + t;
            int r = idx >> 4, k4 = idx & 15;
            float4 av = *(const float4*)&x[(rowBase + r) * 256 + kt + k4 * 4];
            ushort4 h4, l4;
            split4(av, h4, l4);
            *(ushort4*)&Ah[r][k4 * 4] = h4;
            *(ushort4*)&Al[r][k4 * 4] = l4;
            if (p < 2) {   // r in [0,32)
                float4 bv = *(const float4*)&Bw[(colBase + r) * 256 + kt + k4 * 4];
                split4(bv, h4, l4);
                *(ushort4*)&Bh[r][k4 * 4] = h4;
                *(ushort4*)&Bl[r][k4 * 4] = l4;
            }
        }
        __syncthreads();

#pragma unroll
        for (int kk = 0; kk < 64; kk += 32) {
            int ko = kk + quad * 8;
            bf16x8 ah = *(const bf16x8*)&Ah[w * 16 + mr][ko];
            bf16x8 al = *(const bf16x8*)&Al[w * 16 + mr][ko];
#pragma unroll
            for (int nt = 0; nt < 2; nt++) {
                bf16x8 bh = *(const bf16x8*)&Bh[nt * 16 + mr][ko];
                bf16x8 bl = *(const bf16x8*)&Bl[nt * 16 + mr][ko];
                acc[nt] = __builtin_amdgcn_mfma_f32_16x16x32_bf16(ah, bh, acc[nt], 0, 0, 0);
                acc[nt] = __builtin_amdgcn_mfma_f32_16x16x32_bf16(ah, bl, acc[nt], 0, 0, 0);
                acc[nt] = __builtin_amdgcn_mfma_f32_16x16x32_bf16(al, bh, acc[nt], 0, 0, 0);
            }
        }
        __syncthreads();
    }

    // bias + relu -> Dekker split -> hi/lo stores (C/D: col=lane&15, row=quad*4+reg)
#pragma unroll
    for (int nt = 0; nt < 2; nt++) {
        int cg = colBase + nt * 16 + mr;
        float bb = bias[cg];
#pragma unroll
        for (int reg = 0; reg < 4; reg++) {
            int rg = rowBase + w * 16 + quad * 4 + reg;
            float v = fmaxf(acc[nt][reg] + bb, 0.f);
            unsigned short hi = f2bf_rne(v);
            CH[rg * 256 + cg] = hi;
            CL[rg * 256 + cg] = f2bf_rne(v - bf2f(hi));
        }
    }

    // w2 pre-split: 1 elem/thread from each of w2m, w2l
    {
        int off = bid * 256 + t;
        float vm = w2m[off], vl = w2l[off];
        unsigned short h1 = f2bf_rne(vm);
        w2mH[off] = h1; w2mL[off] = f2bf_rne(vm - bf2f(h1));
        unsigned short h2 = f2bf_rne(vl);
        w2lH[off] = h2; w2lL[off] = f2bf_rne(vl - bf2f(h2));
    }

    // moment partials over rows [4*bid, 4*bid+4)
    {
        float sA = 0.f, sB = 0.f;
        int base = bid * 4 * 256 + t;
#pragma unroll
        for (int j = 0; j < 4; j++) {
            float yv = y[base + j * 256];
            float zv = z[base + j * 256];
            sA += yv * yv + zv * zv;
            sB += yv + zv;
        }
        pA1[bid * 256 + t] = sA;
        pB1[bid * 256 + t] = sB;
    }

    // zero rowAcc (consumed by K2 across the kernel boundary)
    if (bid < 4) rowAcc[bid * 256 + t] = 0.f;
}

// ---------------------------------------------------------------------------
// K2: layer-2 GEMM, both heads per block, 32x32 patch, K=256, conversion-free
// + in-block CLUB epilogue. 256 blocks = 32 rowTiles x 8 colTiles.
// Wave w: head=w&1, mtile=w>>1 (rows 16), 2 ntiles (cols 32).
// ---------------------------------------------------------------------------
__global__ __launch_bounds__(256)
void k2_fused(const unsigned short* __restrict__ hmH, const unsigned short* __restrict__ hmL,
              const unsigned short* __restrict__ hlH, const unsigned short* __restrict__ hlL,
              const unsigned short* __restrict__ w2mH, const unsigned short* __restrict__ w2mL,
              const unsigned short* __restrict__ w2lH, const unsigned short* __restrict__ w2lL,
              const float* __restrict__ b2m, const float* __restrict__ b2l,
              const float* __restrict__ y, const float* __restrict__ z,
              const float* __restrict__ pA1, const float* __restrict__ pB1,
              float* __restrict__ rowAcc) {
    const int bid = blockIdx.x, t = threadIdx.x;
    const int rt = bid >> 3, ct = bid & 7;
    const int rowBase = rt * 32, colBase = ct * 32;
    const int w = t >> 6, lane = t & 63, quad = lane >> 4, mr = lane & 15;
    const int h = w & 1, mt = w >> 1;

    __shared__ __align__(16) unsigned short Ast[2][2][32][LSB];  // [head][hi/lo]
    __shared__ __align__(16) unsigned short Bst[2][2][32][LSB];
    __shared__ float Cx[2][32][33];
    __shared__ float part[16][32];
    __shared__ float mAf[32], mBf[32];

    const unsigned short* Aarr[4] = {hmH, hmL, hlH, hlL};
    const unsigned short* Barr[4] = {w2mH, w2mL, w2lH, w2lL};

    // ---- moment fold for this block's 32 cols: 256 partial sets -> means ----
    {
        int c = t & 31, g = t >> 5;    // g 0..7
        int gc = colBase + c;
        float sA = 0.f, sB = 0.f;
        for (int j = 0; j < 32; j++) {
            int s = g * 32 + j;
            sA += pA1[s * 256 + gc];
            sB += pB1[s * 256 + gc];
        }
        part[g][c] = sA;
        part[8 + g][c] = sB;
    }
    __syncthreads();
    if (t < 32) {
        float sA = 0.f, sB = 0.f;
#pragma unroll
        for (int g = 0; g < 8; g++) { sA += part[g][t]; sB += part[8 + g][t]; }
        mAf[t] = sA * (1.f / 1024.f);
        mBf[t] = sB * (1.f / 1024.f);
    }

    f32x4 acc[2] = {{0.f, 0.f, 0.f, 0.f}, {0.f, 0.f, 0.f, 0.f}};

    for (int kt = 0; kt < 256; kt += 64) {
#pragma unroll
        for (int hp = 0; hp < 4; hp++) {    // head*2 + (hi/lo)
#pragma unroll
            for (int p = 0; p < 2; p++) {
                int idx = p * 256 + t;
                int r = idx >> 4, k4 = idx & 15;
                *(ushort4*)&Ast[hp >> 1][hp & 1][r][k4 * 4] =
                    *(const ushort4*)&Aarr[hp][(rowBase + r) * 256 + kt + k4 * 4];
                *(ushort4*)&Bst[hp >> 1][hp & 1][r][k4 * 4] =
                    *(const ushort4*)&Barr[hp][(colBase + r) * 256 + kt + k4 * 4];
            }
        }
        __syncthreads();

#pragma unroll
        for (int kk = 0; kk < 64; kk += 32) {
            int ko = kk + quad * 8;
            bf16x8 ah = *(const bf16x8*)&Ast[h][0][mt * 16 + mr][ko];
            bf16x8 al = *(const bf16x8*)&Ast[h][1][mt * 16 + mr][ko];
#pragma unroll
            for (int nt = 0; nt < 2; nt++) {
                bf16x8 bh = *(const bf16x8*)&Bst[h][0][nt * 16 + mr][ko];
                bf16x8 bl = *(const bf16x8*)&Bst[h][1][nt * 16 + mr][ko];
                acc[nt] = __builtin_amdgcn_mfma_f32_16x16x32_bf16(ah, bh, acc[nt], 0, 0, 0);
                acc[nt] = __builtin_amdgcn_mfma_f32_16x16x32_bf16(ah, bl, acc[nt], 0, 0, 0);
                acc[nt] = __builtin_amdgcn_mfma_f32_16x16x32_bf16(al, bh, acc[nt], 0, 0, 0);
            }
        }
        __syncthreads();
    }

    // ---- exchange mu/lv via LDS (C/D: col=lane&15, row=quad*4+reg) ----
    {
        const float* bias = h ? b2l : b2m;
#pragma unroll
        for (int nt = 0; nt < 2; nt++) {
            int cl = nt * 16 + mr;
            float bb = bias[colBase + cl];
#pragma unroll
            for (int reg = 0; reg < 4; reg++)
                Cx[h][mt * 16 + quad * 4 + reg][cl] = acc[nt][reg] + bb;
        }
    }
    __syncthreads();

    // ---- in-block CLUB epilogue: 32x32 patch, reduce over cols -> rowAcc ----
    {
        int col = t & 31, rg8 = t >> 5;       // 8 row-groups of 4
        int gcol = colBase + col;
        float mA = mAf[col], mB = mBf[col];
#pragma unroll
        for (int r4 = 0; r4 < 4; r4++) {
            int row = rg8 * 4 + r4;
            int o = (rowBase + row) * 256 + gcol;
            float m  = Cx[0][row][col];
            float lv = tanhf(Cx[1][row][col]);
            float iv = 0.5f * expf(-lv);      // 1/(2*exp(logvar))
            float yv = y[o];
            float zv = z[o];
            float Mt = mA - 2.f * m * mB + 2.f * m * m;
            float dy = m - yv, dz = m - zv;
            float term = iv * (Mt - dy * dy - dz * dz);
#pragma unroll
            for (int msk = 16; msk; msk >>= 1)
                term += __shfl_xor(term, msk, 32);
            if (col == 0) atomicAdd(&rowAcc[rowBase + row], term);  // no fence
        }
    }
}

// ---------------------------------------------------------------------------
// K3: 1 block. out = mean_i relu(rowAcc[i]).
// ---------------------------------------------------------------------------
__global__ __launch_bounds__(256)
void k3_final(const float* __restrict__ rowAcc, float* __restrict__ out) {
    __shared__ float red[4];
    int t = threadIdx.x, lane = t & 63, wave = t >> 6;
    float v = 0.f;
#pragma unroll
    for (int p = 0; p < 4; p++)
        v += fmaxf(rowAcc[p * 256 + t], 0.f);
#pragma unroll
    for (int msk = 32; msk; msk >>= 1)
        v += __shfl_xor(v, msk, 64);
    if (lane == 0) red[wave] = v;
    __syncthreads();
    if (t == 0)
        out[0] = (red[0] + red[1] + red[2] + red[3]) * (1.f / 1024.f);
}

// ---------------------------------------------------------------------------
extern "C" void kernel_launch(void* const* d_in, const int* in_sizes, int n_in,
                              void* d_out, int out_size, void* d_ws, size_t ws_size,
                              hipStream_t stream) {
    const float* x   = (const float*)d_in[0];
    const float* y   = (const float*)d_in[1];
    const float* zs  = (const float*)d_in[2];
    const float* w1m = (const float*)d_in[3];
    const float* b1m = (const float*)d_in[4];
    const float* w2m = (const float*)d_in[5];
    const float* b2m = (const float*)d_in[6];
    const float* w1l = (const float*)d_in[7];
    const float* b1l = (const float*)d_in[8];
    const float* w2l = (const float*)d_in[9];
    const float* b2l = (const float*)d_in[10];
    float* out = (float*)d_out;

    char* ws = (char*)d_ws;
    float* pA1    = (float*)(ws);                      // 256 KB
    float* pB1    = (float*)(ws + (256u << 10));       // 256 KB
    float* rowAcc = (float*)(ws + (512u << 10));       // 4 KB
    unsigned short* hmH = (unsigned short*)(ws + (1024u << 10));  // 512 KB each
    unsigned short* hmL = (unsigned short*)(ws + (1536u << 10));
    unsigned short* hlH = (unsigned short*)(ws + (2048u << 10));
    unsigned short* hlL = (unsigned short*)(ws + (2560u << 10));
    unsigned short* w2mH = (unsigned short*)(ws + (3072u << 10)); // 128 KB each
    unsigned short* w2mL = (unsigned short*)(ws + (3200u << 10));
    unsigned short* w2lH = (unsigned short*)(ws + (3328u << 10));
    unsigned short* w2lL = (unsigned short*)(ws + (3456u << 10));

    k1_layer1<<<256, 256, 0, stream>>>(x, w1m, w1l, b1m, b1l, w2m, w2l,
                                       hmH, hmL, hlH, hlL,
                                       w2mH, w2mL, w2lH, w2lL,
                                       y, zs, pA1, pB1, rowAcc);
    k2_fused<<<256, 256, 0, stream>>>(hmH, hmL, hlH, hlL,
                                      w2mH, w2mL, w2lH, w2lL,
                                      b2m, b2l, y, zs, pA1, pB1, rowAcc);
    k3_final<<<1, 256, 0, stream>>>(rowAcc, out);
}

// Round 11
// 91.454 us; speedup vs baseline: 1.7055x; 1.0766x over previous
//
#include <hip/hip_runtime.h>
#include <math.h>

// N=1024, X_DIM=HID=Y_DIM=256. 3 launches. Rules learned: no cross-block
// fences/spins (R4/R9); fire-and-forget atomics fine (R10). This round:
// OCCUPANCY — 512 blocks (2/CU, 2 waves/SIMD) via halved tiles, to hide the
// global/LDS latency that 1-block/CU left fully exposed.
constexpr int LSB = 72;  // bf16 LDS row stride (144 B) — benign banks

typedef short bf16x8 __attribute__((ext_vector_type(8)));
typedef float f32x4  __attribute__((ext_vector_type(4)));

__device__ __forceinline__ unsigned short f2bf_rne(float f) {
    unsigned u = __float_as_uint(f);
    unsigned r = (u + 0x7fff + ((u >> 16) & 1)) >> 16;
    return (unsigned short)r;
}
__device__ __forceinline__ float bf2f(unsigned short h) {
    return __uint_as_float(((unsigned)h) << 16);
}
__device__ __forceinline__ void split4(float4 v, ushort4& hi, ushort4& lo) {
    hi.x = f2bf_rne(v.x); lo.x = f2bf_rne(v.x - bf2f(hi.x));
    hi.y = f2bf_rne(v.y); lo.y = f2bf_rne(v.y - bf2f(hi.y));
    hi.z = f2bf_rne(v.z); lo.z = f2bf_rne(v.z - bf2f(hi.z));
    hi.w = f2bf_rne(v.w); lo.w = f2bf_rne(v.w - bf2f(hi.w));
}

// ---------------------------------------------------------------------------
// K1: layer-1 GEMM, 32x32 tile, K=256, MFMA bf16 split-fp32 (hh+hl+lh).
// 512 blocks: head=bid&1, ct=(bid>>1)&7 (32 cols), rt=bid>>4 (0..31, 32 rows).
// Wave w: mt=w&1 (16 rows), nt=w>>1 (16 cols).
// ---------------------------------------------------------------------------
__global__ __launch_bounds__(256, 2)
void k1_layer1(const float* __restrict__ x,
               const float* __restrict__ w1m, const float* __restrict__ w1l,
               const float* __restrict__ b1m, const float* __restrict__ b1l,
               const float* __restrict__ w2m, const float* __restrict__ w2l,
               unsigned short* __restrict__ hmH, unsigned short* __restrict__ hmL,
               unsigned short* __restrict__ hlH, unsigned short* __restrict__ hlL,
               unsigned short* __restrict__ w2mH, unsigned short* __restrict__ w2mL,
               unsigned short* __restrict__ w2lH, unsigned short* __restrict__ w2lL,
               const float* __restrict__ y, const float* __restrict__ z,
               float* __restrict__ pA1, float* __restrict__ pB1,
               float* __restrict__ rowAcc) {
    const int bid = blockIdx.x, t = threadIdx.x;
    const int head = bid & 1, ct = (bid >> 1) & 7, rt = bid >> 4;
    const int rowBase = rt * 32, colBase = ct * 32;
    const int w = t >> 6, lane = t & 63, quad = lane >> 4, mr = lane & 15;
    const int mt = w & 1, nt = w >> 1;

    const float* Bw   = head ? w1l : w1m;
    const float* bias = head ? b1l : b1m;
    unsigned short* CH = head ? hlH : hmH;
    unsigned short* CL = head ? hlL : hmL;

    __shared__ __align__(16) unsigned short Ah[32][LSB], Al[32][LSB];
    __shared__ __align__(16) unsigned short Bh[32][LSB], Bl[32][LSB];

    f32x4 acc = {0.f, 0.f, 0.f, 0.f};

    for (int kt = 0; kt < 256; kt += 64) {
        // stage 32x64 fp32 tiles of A (x) and B (w1), split to bf16 hi/lo
#pragma unroll
        for (int p = 0; p < 2; p++) {
            int idx = p * 256 + t;
            int r = idx >> 4, k4 = idx & 15;
            float4 av = *(const float4*)&x[(rowBase + r) * 256 + kt + k4 * 4];
            float4 bv = *(const float4*)&Bw[(colBase + r) * 256 + kt + k4 * 4];
            ushort4 h4, l4;
            split4(av, h4, l4);
            *(ushort4*)&Ah[r][k4 * 4] = h4;
            *(ushort4*)&Al[r][k4 * 4] = l4;
            split4(bv, h4, l4);
            *(ushort4*)&Bh[r][k4 * 4] = h4;
            *(ushort4*)&Bl[r][k4 * 4] = l4;
        }
        __syncthreads();

#pragma unroll
        for (int kk = 0; kk < 64; kk += 32) {
            int ko = kk + quad * 8;
            bf16x8 ah = *(const bf16x8*)&Ah[mt * 16 + mr][ko];
            bf16x8 al = *(const bf16x8*)&Al[mt * 16 + mr][ko];
            bf16x8 bh = *(const bf16x8*)&Bh[nt * 16 + mr][ko];
            bf16x8 bl = *(const bf16x8*)&Bl[nt * 16 + mr][ko];
            acc = __builtin_amdgcn_mfma_f32_16x16x32_bf16(ah, bh, acc, 0, 0, 0);
            acc = __builtin_amdgcn_mfma_f32_16x16x32_bf16(ah, bl, acc, 0, 0, 0);
            acc = __builtin_amdgcn_mfma_f32_16x16x32_bf16(al, bh, acc, 0, 0, 0);
        }
        __syncthreads();
    }

    // bias + relu -> Dekker split -> hi/lo stores (C/D: col=lane&15, row=quad*4+reg)
    {
        int cg = colBase + nt * 16 + mr;
        float bb = bias[cg];
#pragma unroll
        for (int reg = 0; reg < 4; reg++) {
            int rg = rowBase + mt * 16 + quad * 4 + reg;
            float v = fmaxf(acc[reg] + bb, 0.f);
            unsigned short hi = f2bf_rne(v);
            CH[rg * 256 + cg] = hi;
            CL[rg * 256 + cg] = f2bf_rne(v - bf2f(hi));
        }
    }

    // w2 pre-split (blocks 0..255 cover 256x256)
    if (bid < 256) {
        int off = bid * 256 + t;
        float vm = w2m[off], vl = w2l[off];
        unsigned short h1 = f2bf_rne(vm);
        w2mH[off] = h1; w2mL[off] = f2bf_rne(vm - bf2f(h1));
        unsigned short h2 = f2bf_rne(vl);
        w2lH[off] = h2; w2lL[off] = f2bf_rne(vl - bf2f(h2));
    }

    // moment partials over rows [4*bid, 4*bid+4) (blocks 0..255)
    if (bid < 256) {
        float sA = 0.f, sB = 0.f;
        int base = bid * 4 * 256 + t;
#pragma unroll
        for (int j = 0; j < 4; j++) {
            float yv = y[base + j * 256];
            float zv = z[base + j * 256];
            sA += yv * yv + zv * zv;
            sB += yv + zv;
        }
        pA1[bid * 256 + t] = sA;
        pB1[bid * 256 + t] = sB;
    }

    // zero rowAcc (consumed by K2 across the kernel boundary)
    if (bid < 4) rowAcc[bid * 256 + t] = 0.f;
}

// ---------------------------------------------------------------------------
// K2: layer-2 GEMM, both heads, 32(rows)x16(cols) patch, K=256,
// conversion-free + in-block CLUB epilogue. 512 blocks = 32 rt x 16 ct.
// Wave w: head=w&1, mt=w>>1 (16 rows), single 16-col ntile.
// ---------------------------------------------------------------------------
__global__ __launch_bounds__(256, 2)
void k2_fused(const unsigned short* __restrict__ hmH, const unsigned short* __restrict__ hmL,
              const unsigned short* __restrict__ hlH, const unsigned short* __restrict__ hlL,
              const unsigned short* __restrict__ w2mH, const unsigned short* __restrict__ w2mL,
              const unsigned short* __restrict__ w2lH, const unsigned short* __restrict__ w2lL,
              const float* __restrict__ b2m, const float* __restrict__ b2l,
              const float* __restrict__ y, const float* __restrict__ z,
              const float* __restrict__ pA1, const float* __restrict__ pB1,
              float* __restrict__ rowAcc) {
    const int bid = blockIdx.x, t = threadIdx.x;
    const int rt = bid >> 4, ct = bid & 15;
    const int rowBase = rt * 32, colBase = ct * 16;
    const int w = t >> 6, lane = t & 63, quad = lane >> 4, mr = lane & 15;
    const int h = w & 1, mt = w >> 1;

    __shared__ __align__(16) unsigned short Ast[2][2][32][LSB];  // [head][hi/lo]
    __shared__ __align__(16) unsigned short Bst[2][2][16][LSB];
    __shared__ float Cx[2][32][17];
    __shared__ float part[16][16];
    __shared__ float mAf[16], mBf[16];

    const unsigned short* Aarr[4] = {hmH, hmL, hlH, hlL};
    const unsigned short* Barr[4] = {w2mH, w2mL, w2lH, w2lL};

    // ---- moment fold for this block's 16 cols: 256 partial sets -> means ----
    {
        int c = t & 15, g = t >> 4;    // g 0..15
        int gc = colBase + c;
        float sA = 0.f, sB = 0.f;
        for (int j = 0; j < 16; j++) {
            int s = g * 16 + j;
            sA += pA1[s * 256 + gc];
        }
        part[g][c] = sA;
    }
    __syncthreads();
    if (t < 16) {
        float sA = 0.f;
#pragma unroll
        for (int g = 0; g < 16; g++) sA += part[g][t];
        mAf[t] = sA * (1.f / 1024.f);
    }
    __syncthreads();
    {
        int c = t & 15, g = t >> 4;
        int gc = colBase + c;
        float sB = 0.f;
        for (int j = 0; j < 16; j++) {
            int s = g * 16 + j;
            sB += pB1[s * 256 + gc];
        }
        part[g][c] = sB;
    }
    __syncthreads();
    if (t < 16) {
        float sB = 0.f;
#pragma unroll
        for (int g = 0; g < 16; g++) sB += part[g][t];
        mBf[t] = sB * (1.f / 1024.f);
    }

    f32x4 acc = {0.f, 0.f, 0.f, 0.f};

    for (int kt = 0; kt < 256; kt += 64) {
#pragma unroll
        for (int hp = 0; hp < 4; hp++) {    // head*2 + (hi/lo)
            // A: 32 rows x 16 k4-units = 512 ushort4 -> 2 iters
#pragma unroll
            for (int p = 0; p < 2; p++) {
                int idx = p * 256 + t;
                int r = idx >> 4, k4 = idx & 15;
                *(ushort4*)&Ast[hp >> 1][hp & 1][r][k4 * 4] =
                    *(const ushort4*)&Aarr[hp][(rowBase + r) * 256 + kt + k4 * 4];
            }
            // B: 16 rows x 16 k4-units = 256 ushort4 -> 1 iter
            {
                int r = t >> 4, k4 = t & 15;
                *(ushort4*)&Bst[hp >> 1][hp & 1][r][k4 * 4] =
                    *(const ushort4*)&Barr[hp][(colBase + r) * 256 + kt + k4 * 4];
            }
        }
        __syncthreads();

#pragma unroll
        for (int kk = 0; kk < 64; kk += 32) {
            int ko = kk + quad * 8;
            bf16x8 ah = *(const bf16x8*)&Ast[h][0][mt * 16 + mr][ko];
            bf16x8 al = *(const bf16x8*)&Ast[h][1][mt * 16 + mr][ko];
            bf16x8 bh = *(const bf16x8*)&Bst[h][0][mr][ko];
            bf16x8 bl = *(const bf16x8*)&Bst[h][1][mr][ko];
            acc = __builtin_amdgcn_mfma_f32_16x16x32_bf16(ah, bh, acc, 0, 0, 0);
            acc = __builtin_amdgcn_mfma_f32_16x16x32_bf16(ah, bl, acc, 0, 0, 0);
            acc = __builtin_amdgcn_mfma_f32_16x16x32_bf16(al, bh, acc, 0, 0, 0);
        }
        __syncthreads();
    }

    // ---- exchange mu/lv via LDS (C/D: col=lane&15, row=quad*4+reg) ----
    {
        const float* bias = h ? b2l : b2m;
        float bb = bias[colBase + mr];
#pragma unroll
        for (int reg = 0; reg < 4; reg++)
            Cx[h][mt * 16 + quad * 4 + reg][mr] = acc[reg] + bb;
    }
    __syncthreads();

    // ---- in-block CLUB epilogue: 32x16 patch; reduce 16 cols -> rowAcc ----
    {
        int col = t & 15, rg = t >> 4;        // rg 0..15, 2 rows each
        int gcol = colBase + col;
        float mA = mAf[col], mB = mBf[col];
#pragma unroll
        for (int rr = 0; rr < 2; rr++) {
            int row = rg * 2 + rr;
            int o = (rowBase + row) * 256 + gcol;
            float m  = Cx[0][row][col];
            float lv = tanhf(Cx[1][row][col]);
            float iv = 0.5f * expf(-lv);      // 1/(2*exp(logvar))
            float yv = y[o];
            float zv = z[o];
            float Mt = mA - 2.f * m * mB + 2.f * m * m;
            float dy = m - yv, dz = m - zv;
            float term = iv * (Mt - dy * dy - dz * dz);
#pragma unroll
            for (int msk = 8; msk; msk >>= 1)
                term += __shfl_xor(term, msk, 16);
            if (col == 0) atomicAdd(&rowAcc[rowBase + row], term);  // no fence
        }
    }
}

// ---------------------------------------------------------------------------
// K3: 1 block. out = mean_i relu(rowAcc[i]).
// ---------------------------------------------------------------------------
__global__ __launch_bounds__(256)
void k3_final(const float* __restrict__ rowAcc, float* __restrict__ out) {
    __shared__ float red[4];
    int t = threadIdx.x, lane = t & 63, wave = t >> 6;
    float v = 0.f;
#pragma unroll
    for (int p = 0; p < 4; p++)
        v += fmaxf(rowAcc[p * 256 + t], 0.f);
#pragma unroll
    for (int msk = 32; msk; msk >>= 1)
        v += __shfl_xor(v, msk, 64);
    if (lane == 0) red[wave] = v;
    __syncthreads();
    if (t == 0)
        out[0] = (red[0] + red[1] + red[2] + red[3]) * (1.f / 1024.f);
}

// ---------------------------------------------------------------------------
extern "C" void kernel_launch(void* const* d_in, const int* in_sizes, int n_in,
                              void* d_out, int out_size, void* d_ws, size_t ws_size,
                              hipStream_t stream) {
    const float* x   = (const float*)d_in[0];
    const float* y   = (const float*)d_in[1];
    const float* zs  = (const float*)d_in[2];
    const float* w1m = (const float*)d_in[3];
    const float* b1m = (const float*)d_in[4];
    const float* w2m = (const float*)d_in[5];
    const float* b2m = (const float*)d_in[6];
    const float* w1l = (const float*)d_in[7];
    const float* b1l = (const float*)d_in[8];
    const float* w2l = (const float*)d_in[9];
    const float* b2l = (const float*)d_in[10];
    float* out = (float*)d_out;

    char* ws = (char*)d_ws;
    float* pA1    = (float*)(ws);                      // 256 KB
    float* pB1    = (float*)(ws + (256u << 10));       // 256 KB
    float* rowAcc = (float*)(ws + (512u << 10));       // 4 KB
    unsigned short* hmH = (unsigned short*)(ws + (1024u << 10));  // 512 KB each
    unsigned short* hmL = (unsigned short*)(ws + (1536u << 10));
    unsigned short* hlH = (unsigned short*)(ws + (2048u << 10));
    unsigned short* hlL = (unsigned short*)(ws + (2560u << 10));
    unsigned short* w2mH = (unsigned short*)(ws + (3072u << 10)); // 128 KB each
    unsigned short* w2mL = (unsigned short*)(ws + (3200u << 10));
    unsigned short* w2lH = (unsigned short*)(ws + (3328u << 10));
    unsigned short* w2lL = (unsigned short*)(ws + (3456u << 10));

    k1_layer1<<<512, 256, 0, stream>>>(x, w1m, w1l, b1m, b1l, w2m, w2l,
                                       hmH, hmL, hlH, hlL,
                                       w2mH, w2mL, w2lH, w2lL,
                                       y, zs, pA1, pB1, rowAcc);
    k2_fused<<<512, 256, 0, stream>>>(hmH, hmL, hlH, hlL,
                                      w2mH, w2mL, w2lH, w2lL,
                                      b2m, b2l, y, zs, pA1, pB1, rowAcc);
    k3_final<<<1, 256, 0, stream>>>(rowAcc, out);
}